// Round 2
// baseline (1052.975 us; speedup 1.0000x reference)
//
#include <hip/hip_runtime.h>
#include <hip/hip_bf16.h>
#include <cstdint>

#define D_   256
#define E_   4096
#define NN_  2048

// ---------------------------------------------------------------------------
// Tiled f32 GEMM: C[M,N] = epilogue(A[M,K] @ B^T + bias)
//   B stored [N,K] row-major (PyTorch Linear weight) unless BT (then [K,N]).
//   GATHER: A row m is concat(x[ei1[m]], x[ei0[m]], eattr[m]) (K=768).
//   SCATTER: atomicAdd into C[ei1[m]] (aggregation). HASADD: += addsrc[m,n].
//   ACT==1: LeakyReLU(0.2).
// 64x64 tile, 256 threads, 4x4 acc per thread, K-chunk 16.
// ---------------------------------------------------------------------------
template<int ACT, bool BT, bool GATHER, bool SCATTER, bool HASADD>
__global__ __launch_bounds__(256)
void gemm_k(const float* __restrict__ A, const float* __restrict__ Bm,
            const float* __restrict__ bias, const float* __restrict__ addsrc,
            float* __restrict__ C, int M, int N, int K,
            const int* __restrict__ ei0, const int* __restrict__ ei1,
            const float* __restrict__ x, const float* __restrict__ eattr)
{
    __shared__ float As[64][17];
    __shared__ float Bs[64][17];
    const int tid = threadIdx.x;
    const int m0 = blockIdx.x * 64;
    const int n0 = blockIdx.y * 64;
    const int ty = tid >> 4, tx = tid & 15;
    const int lrow = tid >> 2, lkq = tid & 3;
    float acc[4][4] = {};

    for (int kk = 0; kk < K; kk += 16) {
        {   // A tile: 64x16, one float4 per thread
            const int m = m0 + lrow;
            const int cb = kk + lkq * 4;
            const float* src;
            if (GATHER) {
                if (cb < 256)      src = x + (size_t)ei1[m] * 256 + cb;
                else if (cb < 512) src = x + (size_t)ei0[m] * 256 + (cb - 256);
                else               src = eattr + (size_t)m * 256 + (cb - 512);
            } else {
                src = A + (size_t)m * K + cb;
            }
            const float4 av = *(const float4*)src;
            As[lrow][lkq*4+0] = av.x; As[lrow][lkq*4+1] = av.y;
            As[lrow][lkq*4+2] = av.z; As[lrow][lkq*4+3] = av.w;
        }
        if (!BT) {
            const int n = n0 + lrow;
            const float4 bv = *(const float4*)(Bm + (size_t)n * K + kk + lkq * 4);
            Bs[lrow][lkq*4+0] = bv.x; Bs[lrow][lkq*4+1] = bv.y;
            Bs[lrow][lkq*4+2] = bv.z; Bs[lrow][lkq*4+3] = bv.w;
        } else {
            // B[n][k] = Bm[k*N + n]  (x @ root case), coalesced over n
            #pragma unroll
            for (int r = 0; r < 4; r++) {
                const int idx = tid + r * 256;
                const int kl = idx >> 6, n = idx & 63;
                Bs[n][kl] = Bm[(size_t)(kk + kl) * N + n0 + n];
            }
        }
        __syncthreads();
        #pragma unroll
        for (int k = 0; k < 16; k++) {
            float a[4], b[4];
            #pragma unroll
            for (int i = 0; i < 4; i++) a[i] = As[ty*4+i][k];
            #pragma unroll
            for (int j = 0; j < 4; j++) b[j] = Bs[tx*4+j][k];
            #pragma unroll
            for (int i = 0; i < 4; i++)
                #pragma unroll
                for (int j = 0; j < 4; j++)
                    acc[i][j] = fmaf(a[i], b[j], acc[i][j]);
        }
        __syncthreads();
    }

    #pragma unroll
    for (int i = 0; i < 4; i++) {
        const int m = m0 + ty*4 + i;
        #pragma unroll
        for (int j = 0; j < 4; j++) {
            const int n = n0 + tx*4 + j;
            float v = acc[i][j] + bias[n];
            if (ACT == 1) v = v > 0.f ? v : 0.2f * v;
            if (HASADD) v += addsrc[(size_t)m * N + n];
            if (SCATTER) {
                atomicAdd(&C[(size_t)ei1[m] * N + n], v);
            } else {
                C[(size_t)m * N + n] = v;
            }
        }
    }
}

// ---------------------------------------------------------------------------
// Mask dtype detection: sample first 8192 words. int32 0/1 masks -> all words
// in {0,1}; packed bool bytes -> words like 0x01010101 (>1). flag=1 => int32.
// ---------------------------------------------------------------------------
__global__ __launch_bounds__(256)
void detect_mask_k(const unsigned int* __restrict__ m, int* __restrict__ flag)
{
    __shared__ int bad;
    if (threadIdx.x == 0) bad = 0;
    __syncthreads();
    int mybad = 0;
    #pragma unroll
    for (int i = 0; i < 32; i++)
        if (m[threadIdx.x + i * 256] > 1u) mybad = 1;
    if (mybad) atomicOr(&bad, 1);
    __syncthreads();
    if (threadIdx.x == 0) *flag = bad ? 0 : 1;
}

// Pack mask (either layout) into bits: pm[row*128 + w] bit j = col w*32+j kept.
__global__ __launch_bounds__(256)
void pack_mask_k(const unsigned char* __restrict__ mraw,
                 unsigned int* __restrict__ pm, const int* __restrict__ flag)
{
    const int t = blockIdx.x * 256 + threadIdx.x;   // 0 .. 524287
    const int row = t >> 7, wb = t & 127;
    unsigned int bits = 0;
    if (*flag) {   // int32 0/1 values
        const uint4* p = (const uint4*)((const int*)mraw + (size_t)row * 4096 + wb * 32);
        #pragma unroll
        for (int g = 0; g < 8; g++) {
            const uint4 v = p[g];
            if (v.x) bits |= 1u << (g*4+0);
            if (v.y) bits |= 1u << (g*4+1);
            if (v.z) bits |= 1u << (g*4+2);
            if (v.w) bits |= 1u << (g*4+3);
        }
    } else {       // 1-byte bools
        const uint4* p = (const uint4*)(mraw + (size_t)row * 4096 + wb * 32);
        #pragma unroll
        for (int g = 0; g < 2; g++) {
            const uint4 v = p[g];
            const unsigned int u[4] = {v.x, v.y, v.z, v.w};
            #pragma unroll
            for (int b2 = 0; b2 < 4; b2++)
                #pragma unroll
                for (int by = 0; by < 4; by++)
                    if ((u[b2] >> (8*by)) & 0xffu) bits |= 1u << (g*16 + b2*4 + by);
        }
    }
    pm[t] = bits;
}

// ---------------------------------------------------------------------------
// Flash attention over edges, f32. Grid: 8 heads x 64 query-tiles (64 rows).
// Block 256 thr = 4 waves; each wave owns 16 rows; 4 lanes per row
// (lane = 4*r + c, c = dim-chunk of 8). Online softmax; masked keys excluded
// (p forced to 0 — equivalent to ref's -10000 additive mask in f32).
// ---------------------------------------------------------------------------
__global__ __launch_bounds__(256)
void attn_k(const float* __restrict__ qkv, const unsigned int* __restrict__ pmask,
            float* __restrict__ o)
{
    __shared__ float ks[64*32];
    __shared__ float vs[64*32];
    const int tid  = threadIdx.x;
    const int wave = tid >> 6, lane = tid & 63;
    const int head = blockIdx.x >> 6;
    const int q0   = (blockIdx.x & 63) * 64;
    const int r = lane >> 2, c = lane & 3;
    const int row = q0 + wave * 16 + r;

    float q[8];
    {
        const float* qp = qkv + (size_t)row * 768 + head * 32 + c * 8;
        const float4 a = *(const float4*)qp;
        const float4 b = *(const float4*)(qp + 4);
        q[0]=a.x;q[1]=a.y;q[2]=a.z;q[3]=a.w;q[4]=b.x;q[5]=b.y;q[6]=b.z;q[7]=b.w;
    }
    float mrun = -1e30f, lrun = 0.f;
    float oa[8] = {};
    const float scale = 0.17677669529663687f; // 1/sqrt(32)

    for (int k0 = 0; k0 < E_; k0 += 64) {
        __syncthreads();
        #pragma unroll
        for (int rep = 0; rep < 2; rep++) {   // stage K,V tiles [64][32]
            const int idx = tid + rep * 256;
            const int j = idx >> 3, q4 = idx & 7;
            const float* kp = qkv + (size_t)(k0 + j) * 768 + 256 + head * 32 + q4 * 4;
            ((float4*)ks)[j*8 + q4] = *(const float4*)kp;
            ((float4*)vs)[j*8 + q4] = *(const float4*)(kp + 256);
        }
        __syncthreads();

        const uint2 mw = *(const uint2*)(pmask + (size_t)row * 128 + (k0 >> 5));
        const unsigned int mlo = mw.x, mhi = mw.y;

        #pragma unroll
        for (int half = 0; half < 2; half++) {
            const unsigned int mbits = half ? mhi : mlo;
            float s[32];
            float tmax = -1e30f;
            #pragma unroll
            for (int j = 0; j < 32; j++) {
                const int jj = half * 32 + j;
                const float4 a = ((const float4*)ks)[jj*8 + c*2];
                const float4 b = ((const float4*)ks)[jj*8 + c*2 + 1];
                float p = q[0]*a.x + q[1]*a.y + q[2]*a.z + q[3]*a.w
                        + q[4]*b.x + q[5]*b.y + q[6]*b.z + q[7]*b.w;
                p += __shfl_xor(p, 1);   // reduce over 4 dim-chunks
                p += __shfl_xor(p, 2);
                p *= scale;
                p = ((mbits >> j) & 1u) ? p : -1e30f;
                s[j] = p;
                tmax = fmaxf(tmax, p);
            }
            const float mnew = fmaxf(mrun, tmax);
            const float f = __expf(mrun - mnew);
            mrun = mnew;
            lrun *= f;
            #pragma unroll
            for (int d = 0; d < 8; d++) oa[d] *= f;
            #pragma unroll
            for (int j = 0; j < 32; j++) {
                const int jj = half * 32 + j;
                float pj = __expf(s[j] - mnew);
                pj = ((mbits >> j) & 1u) ? pj : 0.f;   // hard-zero masked keys
                lrun += pj;
                const float4 a = ((const float4*)vs)[jj*8 + c*2];
                const float4 b = ((const float4*)vs)[jj*8 + c*2 + 1];
                oa[0] = fmaf(pj, a.x, oa[0]); oa[1] = fmaf(pj, a.y, oa[1]);
                oa[2] = fmaf(pj, a.z, oa[2]); oa[3] = fmaf(pj, a.w, oa[3]);
                oa[4] = fmaf(pj, b.x, oa[4]); oa[5] = fmaf(pj, b.y, oa[5]);
                oa[6] = fmaf(pj, b.z, oa[6]); oa[7] = fmaf(pj, b.w, oa[7]);
            }
        }
    }
    const float inv = 1.0f / fmaxf(lrun, 1e-37f);
    float* op = o + (size_t)row * 256 + head * 32 + c * 8;
    float4 o1 = {oa[0]*inv, oa[1]*inv, oa[2]*inv, oa[3]*inv};
    float4 o2 = {oa[4]*inv, oa[5]*inv, oa[6]*inv, oa[7]*inv};
    *(float4*)op = o1;
    *(float4*)(op + 4) = o2;
}

// ---------------------------------------------------------------------------
// LayerNorm over 256 dims, one block per row. var = E[x^2] - E[x]^2 (ddof=0).
// ---------------------------------------------------------------------------
__global__ __launch_bounds__(256)
void ln_k(const float* __restrict__ in, const float* __restrict__ g,
          const float* __restrict__ b, float* __restrict__ out)
{
    const int n = blockIdx.x, t = threadIdx.x;
    const float v = in[(size_t)n * 256 + t];
    float s1 = v, s2 = v * v;
    #pragma unroll
    for (int off = 32; off > 0; off >>= 1) {
        s1 += __shfl_xor(s1, off);
        s2 += __shfl_xor(s2, off);
    }
    __shared__ float r1[4], r2[4];
    const int wv = t >> 6;
    if ((t & 63) == 0) { r1[wv] = s1; r2[wv] = s2; }
    __syncthreads();
    const float t1 = r1[0] + r1[1] + r1[2] + r1[3];
    const float t2 = r2[0] + r2[1] + r2[2] + r2[3];
    const float mu  = t1 * (1.0f / 256.0f);
    const float var = t2 * (1.0f / 256.0f) - mu * mu;
    const float rs  = rsqrtf(var + 1e-5f);
    out[(size_t)n * 256 + t] = (v - mu) * rs * g[t] + b[t];
}

// ---------------------------------------------------------------------------
extern "C" void kernel_launch(void* const* d_in, const int* in_sizes, int n_in,
                              void* d_out, int out_size, void* d_ws, size_t ws_size,
                              hipStream_t stream)
{
    const float* x     = (const float*)d_in[0];
    const int*   ei    = (const int*)  d_in[1];
    const float* eattr = (const float*)d_in[2];
    const unsigned char* mask = (const unsigned char*)d_in[3];
    const float* W1   = (const float*)d_in[4];
    const float* b1   = (const float*)d_in[5];
    const float* W2   = (const float*)d_in[6];
    const float* b2   = (const float*)d_in[7];
    const float* ipw  = (const float*)d_in[8];
    const float* ipb  = (const float*)d_in[9];
    const float* ow   = (const float*)d_in[10];
    const float* ob   = (const float*)d_in[11];
    const float* root = (const float*)d_in[12];
    const float* bp   = (const float*)d_in[13];
    const float* ln1g = (const float*)d_in[14];
    const float* ln1b = (const float*)d_in[15];
    const float* ln2g = (const float*)d_in[16];
    const float* ln2b = (const float*)d_in[17];
    const float* linw = (const float*)d_in[18];
    const float* linb = (const float*)d_in[19];
    const int* ei0 = ei;        // source
    const int* ei1 = ei + E_;   // target

    float* ws = (float*)d_ws;
    float* h1    = ws;             // [E,256]: MLP hidden; attn out o; later z
    float* h     = ws + 1048576;   // [E,256]: messages; later y1
    float* qkv   = ws + 2097152;   // [E,768]; later outb
    float* aggr  = ws + 5242880;   // [N,256]
    unsigned int* pmask = (unsigned int*)(ws + 5767168);  // [4096][128] bits
    int* flag    = (int*)(ws + 6291456);
    float* o    = h1;
    float* outb = qkv;
    float* y1   = h;
    float* z    = h1;

    hipMemsetAsync(aggr, 0, (size_t)NN_ * D_ * sizeof(float), stream);

    dim3 blk(256);
    // mask -> packed bits (layout auto-detected)
    detect_mask_k<<<dim3(1), blk, 0, stream>>>((const unsigned int*)mask, flag);
    pack_mask_k<<<dim3(2048), blk, 0, stream>>>(mask, pmask, flag);

    // S1: h1 = leakyrelu(cat(x_i,x_j,eattr) @ W1^T + b1)
    gemm_k<1,false,true,false,false><<<dim3(64,4), blk, 0, stream>>>(
        nullptr, W1, b1, nullptr, h1, E_, 256, 768, ei0, ei1, x, eattr);
    // S2: h = h1 @ W2^T + b2
    gemm_k<0,false,false,false,false><<<dim3(64,4), blk, 0, stream>>>(
        h1, W2, b2, nullptr, h, E_, 256, 256, nullptr, nullptr, nullptr, nullptr);
    // S3: qkv = h @ in_proj_w^T + in_proj_b
    gemm_k<0,false,false,false,false><<<dim3(64,12), blk, 0, stream>>>(
        h, ipw, ipb, nullptr, qkv, E_, 768, 256, nullptr, nullptr, nullptr, nullptr);
    // S4: masked multi-head attention -> o
    attn_k<<<dim3(512), blk, 0, stream>>>(qkv, pmask, o);
    // S5: msg = o @ out_w^T + out_b, scatter-add to aggr[target]
    gemm_k<0,false,false,true,false><<<dim3(64,4), blk, 0, stream>>>(
        o, ow, ob, nullptr, aggr, E_, 256, 256, nullptr, ei1, nullptr, nullptr);
    // S6: out = x @ root + aggr + bias_p   (root NOT transposed)
    gemm_k<0,true,false,false,true><<<dim3(32,4), blk, 0, stream>>>(
        x, root, bp, aggr, outb, NN_, 256, 256, nullptr, nullptr, nullptr, nullptr);
    // LN1
    ln_k<<<dim3(2048), blk, 0, stream>>>(outb, ln1g, ln1b, y1);
    // F2: z = y1 + y1 @ lin_w^T + lin_b
    gemm_k<0,false,false,false,true><<<dim3(32,4), blk, 0, stream>>>(
        y1, linw, linb, y1, z, NN_, 256, 256, nullptr, nullptr, nullptr, nullptr);
    // LN2 -> out
    ln_k<<<dim3(2048), blk, 0, stream>>>(z, ln2g, ln2b, (float*)d_out);
}

// Round 4
// 366.723 us; speedup vs baseline: 2.8713x; 2.8713x over previous
//
#include <hip/hip_runtime.h>
#include <hip/hip_bf16.h>
#include <cstdint>

#define D_   256
#define E_   4096
#define NN_  2048

typedef float f32x4_t __attribute__((ext_vector_type(4)));
typedef short bf16x8_t __attribute__((ext_vector_type(8)));

__device__ inline short f2bf(float f) {
    union { float fv; unsigned u; } v; v.fv = f;
    unsigned r = v.u + 0x7fffu + ((v.u >> 16) & 1u);
    return (short)(r >> 16);
}

// ---------------------------------------------------------------------------
// Tiled f32 GEMM: C[M,N] = epilogue(A[M,K] @ B^T + bias)
//   OBF16: write output as bf16 (shorts) instead of f32.
// ---------------------------------------------------------------------------
template<int ACT, bool BT, bool GATHER, bool SCATTER, bool HASADD, bool OBF16>
__global__ __launch_bounds__(256)
void gemm_k(const float* __restrict__ A, const float* __restrict__ Bm,
            const float* __restrict__ bias, const float* __restrict__ addsrc,
            float* __restrict__ C, int M, int N, int K,
            const int* __restrict__ ei0, const int* __restrict__ ei1,
            const float* __restrict__ x, const float* __restrict__ eattr)
{
    __shared__ float As[64][17];
    __shared__ float Bs[64][17];
    const int tid = threadIdx.x;
    const int m0 = blockIdx.x * 64;
    const int n0 = blockIdx.y * 64;
    const int ty = tid >> 4, tx = tid & 15;
    const int lrow = tid >> 2, lkq = tid & 3;
    float acc[4][4] = {};

    for (int kk = 0; kk < K; kk += 16) {
        {
            const int m = m0 + lrow;
            const int cb = kk + lkq * 4;
            const float* src;
            if (GATHER) {
                if (cb < 256)      src = x + (size_t)ei1[m] * 256 + cb;
                else if (cb < 512) src = x + (size_t)ei0[m] * 256 + (cb - 256);
                else               src = eattr + (size_t)m * 256 + (cb - 512);
            } else {
                src = A + (size_t)m * K + cb;
            }
            const float4 av = *(const float4*)src;
            As[lrow][lkq*4+0] = av.x; As[lrow][lkq*4+1] = av.y;
            As[lrow][lkq*4+2] = av.z; As[lrow][lkq*4+3] = av.w;
        }
        if (!BT) {
            const int n = n0 + lrow;
            const float4 bv = *(const float4*)(Bm + (size_t)n * K + kk + lkq * 4);
            Bs[lrow][lkq*4+0] = bv.x; Bs[lrow][lkq*4+1] = bv.y;
            Bs[lrow][lkq*4+2] = bv.z; Bs[lrow][lkq*4+3] = bv.w;
        } else {
            #pragma unroll
            for (int r = 0; r < 4; r++) {
                const int idx = tid + r * 256;
                const int kl = idx >> 6, n = idx & 63;
                Bs[n][kl] = Bm[(size_t)(kk + kl) * N + n0 + n];
            }
        }
        __syncthreads();
        #pragma unroll
        for (int k = 0; k < 16; k++) {
            float a[4], b[4];
            #pragma unroll
            for (int i = 0; i < 4; i++) a[i] = As[ty*4+i][k];
            #pragma unroll
            for (int j = 0; j < 4; j++) b[j] = Bs[tx*4+j][k];
            #pragma unroll
            for (int i = 0; i < 4; i++)
                #pragma unroll
                for (int j = 0; j < 4; j++)
                    acc[i][j] = fmaf(a[i], b[j], acc[i][j]);
        }
        __syncthreads();
    }

    #pragma unroll
    for (int i = 0; i < 4; i++) {
        const int m = m0 + ty*4 + i;
        #pragma unroll
        for (int j = 0; j < 4; j++) {
            const int n = n0 + tx*4 + j;
            float v = acc[i][j] + bias[n];
            if (ACT == 1) v = v > 0.f ? v : 0.2f * v;
            if (HASADD) v += addsrc[(size_t)m * N + n];
            if (SCATTER) {
                atomicAdd(&C[(size_t)ei1[m] * N + n], v);
            } else if (OBF16) {
                ((short*)C)[(size_t)m * N + n] = f2bf(v);
            } else {
                C[(size_t)m * N + n] = v;
            }
        }
    }
}

// ---------------------------------------------------------------------------
// Mask dtype detection + bit packing (validated in round 2).
// ---------------------------------------------------------------------------
__global__ __launch_bounds__(256)
void detect_mask_k(const unsigned int* __restrict__ m, int* __restrict__ flag)
{
    __shared__ int bad;
    if (threadIdx.x == 0) bad = 0;
    __syncthreads();
    int mybad = 0;
    #pragma unroll
    for (int i = 0; i < 32; i++)
        if (m[threadIdx.x + i * 256] > 1u) mybad = 1;
    if (mybad) atomicOr(&bad, 1);
    __syncthreads();
    if (threadIdx.x == 0) *flag = bad ? 0 : 1;
}

__global__ __launch_bounds__(256)
void pack_mask_k(const unsigned char* __restrict__ mraw,
                 unsigned int* __restrict__ pm, const int* __restrict__ flag)
{
    const int t = blockIdx.x * 256 + threadIdx.x;
    const int row = t >> 7, wb = t & 127;
    unsigned int bits = 0;
    if (*flag) {
        const uint4* p = (const uint4*)((const int*)mraw + (size_t)row * 4096 + wb * 32);
        #pragma unroll
        for (int g = 0; g < 8; g++) {
            const uint4 v = p[g];
            if (v.x) bits |= 1u << (g*4+0);
            if (v.y) bits |= 1u << (g*4+1);
            if (v.z) bits |= 1u << (g*4+2);
            if (v.w) bits |= 1u << (g*4+3);
        }
    } else {
        const uint4* p = (const uint4*)(mraw + (size_t)row * 4096 + wb * 32);
        #pragma unroll
        for (int g = 0; g < 2; g++) {
            const uint4 v = p[g];
            const unsigned int u[4] = {v.x, v.y, v.z, v.w};
            #pragma unroll
            for (int b2 = 0; b2 < 4; b2++)
                #pragma unroll
                for (int by = 0; by < 4; by++)
                    if ((u[b2] >> (8*by)) & 0xffu) bits |= 1u << (g*16 + b2*4 + by);
        }
    }
    pm[t] = bits;
}

// ---------------------------------------------------------------------------
// MFMA bf16 flash attention. Block = 64 queries x 1 head, 4 waves (16 q each).
// Grid: 8 heads * 64 q-blocks = 512 blocks.
// All LDS tiles use FULL-ADDRESS XOR swizzle, identical formula on write and
// read (rule: both-sides-or-neither, same involution):
//   K  tile [64 keys][32 d] bf16: addr=(key*64 + d*2)  ^ ((key&7)<<4)
//   Vt tile [32 d][64 keys] bf16: addr=(d*128 + key*2) ^ ((d&7)<<4)
//   P  tile [16 q][64 keys] bf16: addr=(q*128 + key*2) ^ ((q&7)<<4)  per wave
// mfma_f32_16x16x32_bf16: A row=l&15, k=(l>>4)*8+j; B col=l&15, k=(l>>4)*8+j;
// C/D col=l&15, row=(l>>4)*4+reg.
// ---------------------------------------------------------------------------
#define KOFF 0
#define VOFF 4096
#define POFF 8192

__global__ __launch_bounds__(256)
void attn_k(const short* __restrict__ qkvb, const unsigned int* __restrict__ pmask,
            float* __restrict__ o)
{
    __shared__ char lds[16384];
    const int tid = threadIdx.x;
    const int w = tid >> 6, l = tid & 63;
    const int g = l >> 4, ln = l & 15;
    const int head = blockIdx.x >> 6;
    const int q0 = (blockIdx.x & 63) * 64;
    const int qw = q0 + w * 16;

    // Q A-frag: query qw+ln, dims g*8..g*8+7 — held in regs all kernel
    const bf16x8_t qf = *(const bf16x8_t*)(qkvb + (size_t)(qw + ln) * 768 + head * 32 + g * 8);

    f32x4_t oacc0 = {0.f,0.f,0.f,0.f};
    f32x4_t oacc1 = {0.f,0.f,0.f,0.f};
    float mrun[4] = {-1e30f,-1e30f,-1e30f,-1e30f};
    float lrun[4] = {0.f,0.f,0.f,0.f};

    const int skey = tid >> 2;   // staging: key row 0..63
    const int sc   = tid & 3;    // staging: dim chunk of 8
    const short* kgp = qkvb + 256 + head*32 + sc*8;
    const short* vgp = qkvb + 512 + head*32 + sc*8;
    char* Pw = lds + POFF + w * 2048;

    for (int k0 = 0; k0 < E_; k0 += 64) {
        __syncthreads();
        {   // stage K + V (transposed), full-address XOR swizzle
            const bf16x8_t kv = *(const bf16x8_t*)(kgp + (size_t)(k0 + skey) * 768);
            *(bf16x8_t*)(lds + KOFF + ((skey*64 + sc*16) ^ ((skey & 7) << 4))) = kv;
            const bf16x8_t vv = *(const bf16x8_t*)(vgp + (size_t)(k0 + skey) * 768);
            #pragma unroll
            for (int j = 0; j < 8; j++) {
                const int d = sc*8 + j;
                *(short*)(lds + VOFF + ((d*128 + skey*2) ^ ((d & 7) << 4))) = vv[j];
            }
        }
        __syncthreads();

        // QK^T: 4 key sub-tiles of 16 -> S C-frags (col=key=ln, rows g*4+r)
        f32x4_t s[4];
        #pragma unroll
        for (int kt = 0; kt < 4; kt++) {
            const int key = kt*16 + ln;
            const bf16x8_t kf = *(const bf16x8_t*)(lds + KOFF + ((key*64 + g*16) ^ ((key & 7) << 4)));
            f32x4_t z = {0.f,0.f,0.f,0.f};
            s[kt] = __builtin_amdgcn_mfma_f32_16x16x32_bf16(qf, kf, z, 0, 0, 0);
        }

        // online softmax per q-row (4 rows per lane), 16-lane shuffle reduces
        float p0[4], p1[4], p2[4], p3[4];
        float fs[4];
        #pragma unroll
        for (int r = 0; r < 4; r++) {
            const int qa = qw + g*4 + r;
            const uint2 mw = *(const uint2*)(pmask + (size_t)qa * 128 + (k0 >> 5));
            float sv[4];
            float tmax = -1e30f;
            #pragma unroll
            for (int kt = 0; kt < 4; kt++) {
                const unsigned word = (kt < 2) ? mw.x : mw.y;
                const unsigned bit = (word >> ((kt & 1) * 16 + ln)) & 1u;
                float v = s[kt][r] * 0.17677669529663687f;
                v = bit ? v : -1e30f;
                sv[kt] = v;
                tmax = fmaxf(tmax, v);
            }
            tmax = fmaxf(tmax, __shfl_xor(tmax, 1));
            tmax = fmaxf(tmax, __shfl_xor(tmax, 2));
            tmax = fmaxf(tmax, __shfl_xor(tmax, 4));
            tmax = fmaxf(tmax, __shfl_xor(tmax, 8));
            const float mnew = fmaxf(mrun[r], tmax);
            const float f = __expf(mrun[r] - mnew);
            mrun[r] = mnew;
            float pv0 = (sv[0] > -1e29f) ? __expf(sv[0] - mnew) : 0.f;
            float pv1 = (sv[1] > -1e29f) ? __expf(sv[1] - mnew) : 0.f;
            float pv2 = (sv[2] > -1e29f) ? __expf(sv[2] - mnew) : 0.f;
            float pv3 = (sv[3] > -1e29f) ? __expf(sv[3] - mnew) : 0.f;
            p0[r]=pv0; p1[r]=pv1; p2[r]=pv2; p3[r]=pv3;
            float ps = pv0 + pv1 + pv2 + pv3;
            ps += __shfl_xor(ps, 1);
            ps += __shfl_xor(ps, 2);
            ps += __shfl_xor(ps, 4);
            ps += __shfl_xor(ps, 8);
            lrun[r] = lrun[r] * f + ps;
            fs[r] = f;
        }
        #pragma unroll
        for (int r = 0; r < 4; r++) { oacc0[r] *= fs[r]; oacc1[r] *= fs[r]; }

        // write P (bf16): FULL-ADDRESS swizzle, same formula as the read
        #pragma unroll
        for (int r = 0; r < 4; r++) {
            const int qi = g*4 + r;
            const int base = qi * 128;
            const int swz = (qi & 7) << 4;
            *(short*)(Pw + ((base + (ln +  0)*2) ^ swz)) = f2bf(p0[r]);
            *(short*)(Pw + ((base + (ln + 16)*2) ^ swz)) = f2bf(p1[r]);
            *(short*)(Pw + ((base + (ln + 32)*2) ^ swz)) = f2bf(p2[r]);
            *(short*)(Pw + ((base + (ln + 48)*2) ^ swz)) = f2bf(p3[r]);
        }

        // PV: O += P·V  (A=P row=q=ln, k=keys; B=Vt col=d=ln, k=keys)
        #pragma unroll
        for (int kh = 0; kh < 2; kh++) {
            const bf16x8_t pf = *(const bf16x8_t*)(Pw + ((ln*128 + kh*64 + g*16) ^ ((ln & 7) << 4)));
            {
                const int d = ln;
                const bf16x8_t vf = *(const bf16x8_t*)(lds + VOFF + ((d*128 + kh*64 + g*16) ^ ((d & 7) << 4)));
                oacc0 = __builtin_amdgcn_mfma_f32_16x16x32_bf16(pf, vf, oacc0, 0, 0, 0);
            }
            {
                const int d = 16 + ln;
                const bf16x8_t vf = *(const bf16x8_t*)(lds + VOFF + ((d*128 + kh*64 + g*16) ^ ((d & 7) << 4)));
                oacc1 = __builtin_amdgcn_mfma_f32_16x16x32_bf16(pf, vf, oacc1, 0, 0, 0);
            }
        }
    }

    #pragma unroll
    for (int r = 0; r < 4; r++) {
        const float inv = 1.0f / fmaxf(lrun[r], 1e-37f);
        const int qa = qw + g*4 + r;
        o[(size_t)qa * 256 + head*32 +  0 + ln] = oacc0[r] * inv;
        o[(size_t)qa * 256 + head*32 + 16 + ln] = oacc1[r] * inv;
    }
}

// ---------------------------------------------------------------------------
// LayerNorm over 256 dims, one block per row.
// ---------------------------------------------------------------------------
__global__ __launch_bounds__(256)
void ln_k(const float* __restrict__ in, const float* __restrict__ g,
          const float* __restrict__ b, float* __restrict__ out)
{
    const int n = blockIdx.x, t = threadIdx.x;
    const float v = in[(size_t)n * 256 + t];
    float s1 = v, s2 = v * v;
    #pragma unroll
    for (int off = 32; off > 0; off >>= 1) {
        s1 += __shfl_xor(s1, off);
        s2 += __shfl_xor(s2, off);
    }
    __shared__ float r1[4], r2[4];
    const int wv = t >> 6;
    if ((t & 63) == 0) { r1[wv] = s1; r2[wv] = s2; }
    __syncthreads();
    const float t1 = r1[0] + r1[1] + r1[2] + r1[3];
    const float t2 = r2[0] + r2[1] + r2[2] + r2[3];
    const float mu  = t1 * (1.0f / 256.0f);
    const float var = t2 * (1.0f / 256.0f) - mu * mu;
    const float rs  = rsqrtf(var + 1e-5f);
    out[(size_t)n * 256 + t] = (v - mu) * rs * g[t] + b[t];
}

// ---------------------------------------------------------------------------
extern "C" void kernel_launch(void* const* d_in, const int* in_sizes, int n_in,
                              void* d_out, int out_size, void* d_ws, size_t ws_size,
                              hipStream_t stream)
{
    const float* x     = (const float*)d_in[0];
    const int*   ei    = (const int*)  d_in[1];
    const float* eattr = (const float*)d_in[2];
    const unsigned char* mask = (const unsigned char*)d_in[3];
    const float* W1   = (const float*)d_in[4];
    const float* b1   = (const float*)d_in[5];
    const float* W2   = (const float*)d_in[6];
    const float* b2   = (const float*)d_in[7];
    const float* ipw  = (const float*)d_in[8];
    const float* ipb  = (const float*)d_in[9];
    const float* ow   = (const float*)d_in[10];
    const float* ob   = (const float*)d_in[11];
    const float* root = (const float*)d_in[12];
    const float* bp   = (const float*)d_in[13];
    const float* ln1g = (const float*)d_in[14];
    const float* ln1b = (const float*)d_in[15];
    const float* ln2g = (const float*)d_in[16];
    const float* ln2b = (const float*)d_in[17];
    const float* linw = (const float*)d_in[18];
    const float* linb = (const float*)d_in[19];
    const int* ei0 = ei;
    const int* ei1 = ei + E_;

    float* ws = (float*)d_ws;
    float* h1    = ws;                              // [E,256]; later attn o; later z
    float* h     = ws + 1048576;                    // [E,256]; later y1
    short* qkvb  = (short*)(ws + 2097152);          // [E,768] bf16
    float* aggr  = ws + 3670016;                    // [N,256]
    float* outb  = ws + 4194304;                    // [N,256]
    unsigned int* pmask = (unsigned int*)(ws + 4718592);  // [4096][128] bits
    int* flag    = (int*)(ws + 5242880);
    float* o    = h1;
    float* y1   = h;
    float* z    = h1;

    hipMemsetAsync(aggr, 0, (size_t)NN_ * D_ * sizeof(float), stream);

    dim3 blk(256);
    detect_mask_k<<<dim3(1), blk, 0, stream>>>((const unsigned int*)mask, flag);
    pack_mask_k<<<dim3(2048), blk, 0, stream>>>(mask, pmask, flag);

    // S1: h1 = leakyrelu(cat(x_i,x_j,eattr) @ W1^T + b1)
    gemm_k<1,false,true,false,false,false><<<dim3(64,4), blk, 0, stream>>>(
        nullptr, W1, b1, nullptr, h1, E_, 256, 768, ei0, ei1, x, eattr);
    // S2: h = h1 @ W2^T + b2
    gemm_k<0,false,false,false,false,false><<<dim3(64,4), blk, 0, stream>>>(
        h1, W2, b2, nullptr, h, E_, 256, 256, nullptr, nullptr, nullptr, nullptr);
    // S3: qkvb = bf16(h @ in_proj_w^T + in_proj_b)
    gemm_k<0,false,false,false,false,true><<<dim3(64,12), blk, 0, stream>>>(
        h, ipw, ipb, nullptr, (float*)qkvb, E_, 768, 256, nullptr, nullptr, nullptr, nullptr);
    // S4: MFMA flash attention -> o (f32)
    attn_k<<<dim3(512), blk, 0, stream>>>(qkvb, pmask, o);
    // S5: msg = o @ out_w^T + out_b, scatter-add to aggr[target]
    gemm_k<0,false,false,true,false,false><<<dim3(64,4), blk, 0, stream>>>(
        o, ow, ob, nullptr, aggr, E_, 256, 256, nullptr, ei1, nullptr, nullptr);
    // S6: out = x @ root + aggr + bias_p
    gemm_k<0,true,false,false,true,false><<<dim3(32,4), blk, 0, stream>>>(
        x, root, bp, aggr, outb, NN_, 256, 256, nullptr, nullptr, nullptr, nullptr);
    // LN1
    ln_k<<<dim3(2048), blk, 0, stream>>>(outb, ln1g, ln1b, y1);
    // F2: z = y1 + y1 @ lin_w^T + lin_b
    gemm_k<0,false,false,false,true,false><<<dim3(32,4), blk, 0, stream>>>(
        y1, linw, linb, y1, z, NN_, 256, 256, nullptr, nullptr, nullptr, nullptr);
    // LN2 -> out
    ln_k<<<dim3(2048), blk, 0, stream>>>(z, ln2g, ln2b, (float*)d_out);
}